// Round 1
// baseline (61.293 us; speedup 1.0000x reference)
//
#include <hip/hip_runtime.h>
#include <stdint.h>

typedef __attribute__((ext_vector_type(8))) short short8;
typedef __attribute__((ext_vector_type(4))) float f32x4;

#define N_ROWS 4096
#define D_DIM  256
#define NT     8192
#define TILE   128
#define NTILE  64   // 8192 / 128

__device__ __forceinline__ unsigned short f2bf(float f) {
  unsigned int u = __float_as_uint(f);
  u += 0x7fffu + ((u >> 16) & 1u);          // round-to-nearest-even
  return (unsigned short)(u >> 16);
}

__device__ __forceinline__ void gload_lds16(const void* g, void* l) {
  __builtin_amdgcn_global_load_lds(
      (const __attribute__((address_space(1))) unsigned int*)g,
      (__attribute__((address_space(3))) unsigned int*)l, 16, 0, 0);
}

// ---------------- prep: f32 -> bf16 + exact f32 row norms ----------------
__global__ __launch_bounds__(256) void mmd_prep(
    const float* __restrict__ x1, const float* __restrict__ x2,
    unsigned short* __restrict__ Zb, float* __restrict__ norms) {
  const int t = threadIdx.x, w = t >> 6, l = t & 63;
  const int r = blockIdx.x * 4 + w;                      // one wave per row
  const float* src = (r < N_ROWS) ? (x1 + (size_t)r * D_DIM)
                                  : (x2 + (size_t)(r - N_ROWS) * D_DIM);
  const float4 v = *(const float4*)(src + l * 4);
  float sq = v.x * v.x + v.y * v.y + v.z * v.z + v.w * v.w;
#pragma unroll
  for (int off = 32; off > 0; off >>= 1) sq += __shfl_down(sq, off);
  if (l == 0) norms[r] = sq;
  ushort4 o;
  o.x = f2bf(v.x); o.y = f2bf(v.y); o.z = f2bf(v.z); o.w = f2bf(v.w);
  *(ushort4*)(Zb + (size_t)r * D_DIM + l * 4) = o;
}

// ---------------- main: lower-triangular tiles of G = Z Z^T + fused exp-sum ----
__global__ __launch_bounds__(256) void mmd_main(
    const unsigned short* __restrict__ Zb,
    const float* __restrict__ norms,
    float* __restrict__ partials) {
  const int br = blockIdx.x, bc = blockIdx.y;
  const int pidx = br * NTILE + bc;
  const int t = threadIdx.x;
  if (bc > br) { if (t == 0) partials[pidx] = 0.0f; return; }   // symmetry

  __shared__ __align__(16) unsigned short As[TILE][32];
  __shared__ __align__(16) unsigned short Bs[TILE][32];
  __shared__ float nrow[TILE], ncol[TILE];
  __shared__ float red[256];

  const int w = t >> 6, l = t & 63;
  if (t < TILE) nrow[t] = norms[br * TILE + t];
  else          ncol[t - TILE] = norms[bc * TILE + (t - TILE)];

  const int wr = (w >> 1) * 64, wc = (w & 1) * 64;   // wave -> 64x64 sub-tile
  const int fr = l & 15, fq = l >> 4;

  f32x4 acc[4][4];
#pragma unroll
  for (int m = 0; m < 4; ++m)
#pragma unroll
    for (int n = 0; n < 4; ++n)
      acc[m][n] = (f32x4){0.0f, 0.0f, 0.0f, 0.0f};

  for (int k0 = 0; k0 < D_DIM; k0 += 32) {
    // stage A(128x32) and B(128x32) bf16 tiles: per wave 2x 1KB chunks each,
    // LDS dest wave-uniform base (+lane*16 by HW), global source per-lane.
#pragma unroll
    for (int q = 0; q < 2; ++q) {
      const int obase = w * 2048 + q * 1024;          // bytes into tile
      const int o = obase + l * 16;
      const int row = o >> 6;                         // 64 B per row (32 bf16)
      const int chunk = (o >> 4) & 3;
      const unsigned short* ga =
          Zb + (size_t)(br * TILE + row) * D_DIM + k0 + chunk * 8;
      const unsigned short* gb =
          Zb + (size_t)(bc * TILE + row) * D_DIM + k0 + chunk * 8;
      gload_lds16(ga, (char*)(&As[0][0]) + obase);
      gload_lds16(gb, (char*)(&Bs[0][0]) + obase);
    }
    __syncthreads();

    short8 a[4], b[4];
#pragma unroll
    for (int m = 0; m < 4; ++m)
      a[m] = *(const short8*)(&As[wr + m * 16 + fr][fq * 8]);
#pragma unroll
    for (int n = 0; n < 4; ++n)
      b[n] = *(const short8*)(&Bs[wc + n * 16 + fr][fq * 8]);
#pragma unroll
    for (int m = 0; m < 4; ++m)
#pragma unroll
      for (int n = 0; n < 4; ++n)
        acc[m][n] = __builtin_amdgcn_mfma_f32_16x16x32_bf16(a[m], b[n],
                                                            acc[m][n], 0, 0, 0);
    __syncthreads();
  }

  // epilogue: d = |xi|^2 + |xj|^2 - 2 dot; sum_g exp(-c_g d),
  // c = {8,2,0.32,0.08,0.02} = 0.02 * {400,100,16,4,1} -> powers of one exp.
  float factor = ((br < 32) == (bc < 32)) ? 1.0f : -1.0f;  // same-side vs cross
  if (br != bc) factor *= 2.0f;                            // off-diag tile: x2
  const bool diag = (br == bc);

  float sum = 0.0f;
#pragma unroll
  for (int m = 0; m < 4; ++m) {
#pragma unroll
    for (int n = 0; n < 4; ++n) {
#pragma unroll
      for (int r = 0; r < 4; ++r) {
        const int i = wr + m * 16 + fq * 4 + r;   // C layout: row=(l>>4)*4+reg
        const int j = wc + n * 16 + fr;           //           col=l&15
        float d = nrow[i] + ncol[j] - 2.0f * acc[m][n][r];
        d = fmaxf(d, 0.0f);
        const float u = __expf(-0.02f * d);
        const float u2 = u * u, u4 = u2 * u2;
        const float u8 = u4 * u4, u16 = u8 * u8;
        const float u32v = u16 * u16, u64v = u32v * u32v;
        const float u100 = u64v * u32v * u4;
        const float u200 = u100 * u100, u400 = u200 * u200;
        float S = u + u4 + u16 + u100 + u400;
        if (diag && i == j) S = 0.0f;             // diagonal added analytically
        sum += S;
      }
    }
  }
  sum *= factor;

  red[t] = sum;
  __syncthreads();
#pragma unroll
  for (int k = 128; k > 0; k >>= 1) {
    if (t < k) red[t] += red[t + k];
    __syncthreads();
  }
  if (t == 0) partials[pidx] = red[0];
}

// ---------------- finish: deterministic sum + diagonal constant + sqrt -------
__global__ __launch_bounds__(256) void mmd_finish(
    const float* __restrict__ partials, float* __restrict__ out) {
  __shared__ float red[256];
  const int t = threadIdx.x;
  float s = 0.0f;
  for (int i = t; i < NTILE * NTILE; i += 256) s += partials[i];
  red[t] = s;
  __syncthreads();
#pragma unroll
  for (int k = 128; k > 0; k >>= 1) {
    if (t < k) red[t] += red[t + k];
    __syncthreads();
  }
  if (t == 0) {
    const float total = red[0] + 40960.0f;   // 2*4096 diag elems * 5 gammas
    out[0] = sqrtf(fmaxf(total, 0.0f) / 83886080.0f);  // / (5 * 4096^2)
  }
}

extern "C" void kernel_launch(void* const* d_in, const int* in_sizes, int n_in,
                              void* d_out, int out_size, void* d_ws, size_t ws_size,
                              hipStream_t stream) {
  const float* x1 = (const float*)d_in[0];
  const float* x2 = (const float*)d_in[1];
  unsigned short* Zb = (unsigned short*)d_ws;                       // 4 MiB bf16 Z
  float* norms = (float*)((char*)d_ws + (size_t)NT * D_DIM * 2);    // 32 KiB
  float* partials = norms + NT;                                     // 16 KiB
  float* out = (float*)d_out;

  mmd_prep<<<dim3(NT / 4), dim3(256), 0, stream>>>(x1, x2, Zb, norms);
  mmd_main<<<dim3(NTILE, NTILE), dim3(256), 0, stream>>>(Zb, norms, partials);
  mmd_finish<<<dim3(1), dim3(256), 0, stream>>>(partials, out);
}